// Round 3
// baseline (252.802 us; speedup 1.0000x reference)
//
#include <hip/hip_runtime.h>

typedef __attribute__((ext_vector_type(8))) __bf16 bf16x8;
typedef __attribute__((ext_vector_type(4))) float f32x4;

#define DI __device__ __forceinline__

// float -> bf16 bits, RNE
DI unsigned short f2bf(float x) {
  unsigned u = __float_as_uint(x);
  u += 0x7fffu + ((u >> 16) & 1u);
  return (unsigned short)(u >> 16);
}

DI bf16x8 cvt8(f32x4 lo, f32x4 hi) {
  bf16x8 r;
  r[0] = (__bf16)lo.x; r[1] = (__bf16)lo.y; r[2] = (__bf16)lo.z; r[3] = (__bf16)lo.w;
  r[4] = (__bf16)hi.x; r[5] = (__bf16)hi.y; r[6] = (__bf16)hi.z; r[7] = (__bf16)hi.w;
  return r;
}

DI float tanh_fast(float x) {
  float ax = fabsf(x);
  float e = __expf(-2.0f * ax);
  float t = (1.0f - e) / (1.0f + e);
  return x < 0.0f ? -t : t;
}

// Raw barrier, fenced against compiler reordering. No vmem drain.
DI void barx() {
  __builtin_amdgcn_sched_barrier(0);
  __builtin_amdgcn_s_barrier();
  __builtin_amdgcn_sched_barrier(0);
}

// Drain LDS ops before a barrier that publishes ds_writes (rule #18).
DI void lgkm0() {
  __builtin_amdgcn_sched_barrier(0);
  asm volatile("s_waitcnt lgkmcnt(0)" ::: "memory");
  __builtin_amdgcn_sched_barrier(0);
}

// ---------------------------------------------------------------------------
// Kernel 0: W [512(k),256(n)] fp32 -> Wt [256(n),512(k)] bf16 (B^T layout).
// ---------------------------------------------------------------------------
__global__ void k_wt(const float* __restrict__ W, unsigned short* __restrict__ Wt) {
  int n = blockIdx.x;
  int t = threadIdx.x;     // 0..127
  int k = t * 4;
  ushort4 v;
  v.x = f2bf(W[(k + 0) * 256 + n]);
  v.y = f2bf(W[(k + 1) * 256 + n]);
  v.z = f2bf(W[(k + 2) * 256 + n]);
  v.w = f2bf(W[(k + 3) * 256 + n]);
  *(ushort4*)&Wt[n * 512 + k] = v;
}

// ---------------------------------------------------------------------------
// Kernel 1: projection GEMM. M=65536, K=512, N=256.
// Tile 256x256 (grid=256 -> exactly 1 block/CU, single round; halves B
// traffic vs 128-tile). 8 waves (2x4), wave-tile 128x64. BK=64, 8 K-steps.
// Reg-staged pipeline (T14): loads for tile t+1 issued one full compute
// phase ahead into VGPRs; A converted fp32->bf16 in regs; single 64 KB LDS
// buffer (As+Bs bf16). Per step: compute(t); bar; ds_write(t+1);
// issue(t+2); lgkmcnt(0); bar.  No vmem drain at barriers.
// XOR swizzle applied identically on ds_write and ds_read (chunk ^ row&7).
// ---------------------------------------------------------------------------
__global__ __launch_bounds__(512, 2) void k_proj(
    const float* __restrict__ Alt, const float* __restrict__ Art,
    const unsigned short* __restrict__ Wt, const float* __restrict__ diag,
    unsigned short* __restrict__ Olt, unsigned short* __restrict__ Ort) {
  __shared__ __align__(16) unsigned short As[256 * 64];  // 32 KB bf16
  __shared__ __align__(16) unsigned short Bs[256 * 64];  // 32 KB bf16

  int bx = blockIdx.x;              // 0..255
  bool is_lt = bx < 128;
  int m0 = (is_lt ? bx : bx - 128) * 256;
  const char* Abase = (const char*)((is_lt ? Alt : Art) + (size_t)m0 * 512);
  unsigned short* O = (is_lt ? Olt : Ort) + (size_t)m0 * 256;
  const char* Bbase = (const char*)Wt;

  int tid  = threadIdx.x;
  int lane = tid & 63;
  int wid  = tid >> 6;              // 0..7
  int wm   = wid >> 2;              // 0..1 -> 128-row half
  int wn   = wid & 3;               // 0..3 -> 64-col group
  int l15  = lane & 15;
  int quad = lane >> 4;
  int r7   = l15 & 7;

  // Staging geometry: wave stages rows wid*32 + j*8 + (lane>>3); chunk lane&7.
  int srow = wid * 32 + (lane >> 3);
  int sc   = lane & 7;
  int wch  = ((sc ^ (lane >> 3)) << 4);   // swizzled chunk byte (row&7 == lane>>3)

  char* AsB = (char*)As;
  char* BsB = (char*)Bs;

  f32x4 zero = {0.0f, 0.0f, 0.0f, 0.0f};
  f32x4 acc[8][4];
#pragma unroll
  for (int i = 0; i < 8; i++)
#pragma unroll
    for (int j = 0; j < 4; j++) acc[i][j] = zero;

  f32x4 aLo[4], aHi[4];     // raw fp32 A, tile in flight
  uint4 bR[4];              // raw bf16 B rows, tile in flight

  auto issue = [&](int t) {
#pragma unroll
    for (int j = 0; j < 4; j++) {
      const char* ap = Abase + (size_t)(srow + j * 8) * 2048 + t * 256 + sc * 32;
      aLo[j] = *(const f32x4*)(ap);
      aHi[j] = *(const f32x4*)(ap + 16);
      bR[j]  = *(const uint4*)(Bbase + (size_t)(srow + j * 8) * 1024 + t * 128 + sc * 16);
    }
  };
  auto writeS = [&]() {
#pragma unroll
    for (int j = 0; j < 4; j++) {
      int r = srow + j * 8;
      *(bf16x8*)(AsB + r * 128 + wch) = cvt8(aLo[j], aHi[j]);
      *(uint4*)(BsB + r * 128 + wch) = bR[j];
    }
  };
  auto compute = [&]() {
#pragma unroll
    for (int ks = 0; ks < 2; ks++) {
      bf16x8 a[8], b[4];
#pragma unroll
      for (int mt = 0; mt < 8; mt++) {
        int row = wm * 128 + mt * 16 + l15;
        int c = ks * 4 + quad;
        a[mt] = *(const bf16x8*)(AsB + row * 128 + ((c ^ r7) << 4));
      }
#pragma unroll
      for (int nt = 0; nt < 4; nt++) {
        int row = wn * 64 + nt * 16 + l15;
        int c = ks * 4 + quad;
        b[nt] = *(const bf16x8*)(BsB + row * 128 + ((c ^ r7) << 4));
      }
      __builtin_amdgcn_s_setprio(1);
#pragma unroll
      for (int mt = 0; mt < 8; mt++)
#pragma unroll
        for (int nt = 0; nt < 4; nt++)
          acc[mt][nt] = __builtin_amdgcn_mfma_f32_16x16x32_bf16(a[mt], b[nt], acc[mt][nt], 0, 0, 0);
      __builtin_amdgcn_s_setprio(0);
    }
  };

  // Prologue: tile 0 -> LDS; tile 1 loads in flight.
  issue(0);
  writeS();          // compiler inserts the vmcnt wait for the reg uses
  issue(1);
  lgkm0();
  barx();

  for (int t = 0; t < 8; t++) {
    compute();                      // tile t, while tile t+1 loads fly
    if (t < 7) {
      barx();                       // all waves done reading S
      writeS();                     // tile t+1 regs -> LDS (auto vm wait)
      if (t < 6) issue(t + 2);      // next tile's loads into freed regs
      lgkm0();
      barx();                       // S(t+1) visible to all
    }
  }

  // Epilogue: tanh, diag scale (lt only), bf16 store.
  float dscale[4];
#pragma unroll
  for (int nt = 0; nt < 4; nt++)
    dscale[nt] = is_lt ? diag[wn * 64 + nt * 16 + l15] : 1.0f;

#pragma unroll
  for (int mt = 0; mt < 8; mt++) {
#pragma unroll
    for (int r = 0; r < 4; r++) {
      int row = wm * 128 + mt * 16 + quad * 4 + r;
#pragma unroll
      for (int nt = 0; nt < 4; nt++) {
        int col = wn * 64 + nt * 16 + l15;
        O[(size_t)row * 256 + col] = f2bf(tanh_fast(acc[mt][nt][r]) * dscale[nt]);
      }
    }
  }
}

// ---------------------------------------------------------------------------
// Kernel 2: per-batch logits (lt_b @ rt_b^T, K=256) + fused exact softmax.
// Block 64(L) x 512(R), 8 waves (64x64 tiles, wid = col-group).
// L tile (64x256, 32 KB) staged ONCE for the whole K in the prologue.
// K-loop stages only R at BK=32 (32 KB single LDS buffer) with the same
// reg-staged issue-early/write-late pipeline. 8 K-steps.
// LDS ~67 KB. XCD batch swizzle retained.
// ---------------------------------------------------------------------------
__global__ __launch_bounds__(512, 2) void k_attn(
    const unsigned short* __restrict__ Lt, const unsigned short* __restrict__ Rt,
    float* __restrict__ Out) {
  __shared__ __align__(16) unsigned short Ls[64 * 256];   // 32 KB, whole K
  __shared__ __align__(16) unsigned short Rs[512 * 32];   // 32 KB, one BK=32 tile
  __shared__ float red[8][64];
  __shared__ float rowv[64];

  int bx = blockIdx.x;                       // 0..511
  int b  = (bx & 7) * 8 + ((bx >> 3) & 7);   // batch, XCD-co-located
  int l0 = (bx >> 6) * 64;
  const char* Lb = (const char*)(Lt + ((size_t)b * 512 + l0) * 256);
  const char* Rb = (const char*)(Rt + (size_t)b * 512 * 256);
  float* Ob = Out + ((size_t)b * 512 + l0) * 512;

  int tid  = threadIdx.x;
  int lane = tid & 63;
  int wid  = tid >> 6;              // 0..7 -> 64-col group
  int l15  = lane & 15;
  int quad = lane >> 4;
  int r7   = l15 & 7;
  int swb  = (l15 >> 1) & 3;        // Rs read swizzle ((row>>1)&3, lane part)
  int swr  = (tid >> 1) & 3;        // Rs write swizzle (row = tid)

  char* LsB = (char*)Ls;
  char* RsB = (char*)Rs;

  f32x4 zero = {0.0f, 0.0f, 0.0f, 0.0f};
  f32x4 acc[4][4];
#pragma unroll
  for (int i = 0; i < 4; i++)
#pragma unroll
    for (int j = 0; j < 4; j++) acc[i][j] = zero;

  uint4 rR[4];                      // R tile in flight (row = tid, 64 B)
  auto issueR = [&](int t) {
#pragma unroll
    for (int j = 0; j < 4; j++)
      rR[j] = *(const uint4*)(Rb + (size_t)tid * 512 + t * 64 + j * 16);
  };
  auto writeR = [&]() {
#pragma unroll
    for (int j = 0; j < 4; j++)
      *(uint4*)(RsB + tid * 64 + ((j ^ swr) << 4)) = rR[j];
  };

  // ---- prologue: whole-K L tile + R tile 0; R tile 1 in flight ----
  {
    int rowL = tid >> 3, cL = tid & 7;
    uint4 lL[4];
#pragma unroll
    for (int j = 0; j < 4; j++)
      lL[j] = *(const uint4*)(Lb + (size_t)rowL * 512 + cL * 64 + j * 16);
#pragma unroll
    for (int j = 0; j < 4; j++) {
      int ch = cL * 4 + j;
      *(uint4*)(LsB + rowL * 512 + ((ch ^ (rowL & 7)) << 4)) = lL[j];
    }
  }
  issueR(0);
  writeR();
  issueR(1);
  lgkm0();
  barx();

  for (int t = 0; t < 8; t++) {
    // compute tile t (BK=32 -> one ks)
    bf16x8 a[4], bb[4];
#pragma unroll
    for (int mt = 0; mt < 4; mt++) {
      int row = mt * 16 + l15;
      int c = t * 4 + quad;
      a[mt] = *(const bf16x8*)(LsB + row * 512 + ((c ^ r7) << 4));
    }
#pragma unroll
    for (int nt = 0; nt < 4; nt++) {
      int row = wid * 64 + nt * 16 + l15;
      bb[nt] = *(const bf16x8*)(RsB + row * 64 + ((quad ^ swb) << 4));
    }
    __builtin_amdgcn_s_setprio(1);
#pragma unroll
    for (int mt = 0; mt < 4; mt++)
#pragma unroll
      for (int nt = 0; nt < 4; nt++)
        acc[mt][nt] = __builtin_amdgcn_mfma_f32_16x16x32_bf16(a[mt], bb[nt], acc[mt][nt], 0, 0, 0);
    __builtin_amdgcn_s_setprio(0);

    if (t < 7) {
      barx();                       // all waves done reading Rs
      writeR();                     // tile t+1 regs -> LDS
      if (t < 6) issueR(t + 2);
      lgkm0();
      barx();                       // Rs(t+1) visible
    }
  }

  // -------- softmax over the 512-wide row (8 col-groups) --------
#pragma unroll
  for (int mt = 0; mt < 4; mt++) {
#pragma unroll
    for (int r = 0; r < 4; r++) {
      float m = fmaxf(fmaxf(acc[mt][0][r], acc[mt][1][r]),
                      fmaxf(acc[mt][2][r], acc[mt][3][r]));
      m = fmaxf(m, __shfl_xor(m, 1));
      m = fmaxf(m, __shfl_xor(m, 2));
      m = fmaxf(m, __shfl_xor(m, 4));
      m = fmaxf(m, __shfl_xor(m, 8));
      if (l15 == 0) red[wid][mt * 16 + quad * 4 + r] = m;
    }
  }
  __syncthreads();
  if (tid < 64) {
    float m = red[0][tid];
#pragma unroll
    for (int w = 1; w < 8; w++) m = fmaxf(m, red[w][tid]);
    rowv[tid] = m;
  }
  __syncthreads();

#pragma unroll
  for (int mt = 0; mt < 4; mt++) {
#pragma unroll
    for (int r = 0; r < 4; r++) {
      float base = rowv[mt * 16 + quad * 4 + r];
      float s = 0.0f;
#pragma unroll
      for (int nt = 0; nt < 4; nt++) {
        float e = __expf(acc[mt][nt][r] - base);
        acc[mt][nt][r] = e;
        s += e;
      }
      s += __shfl_xor(s, 1);
      s += __shfl_xor(s, 2);
      s += __shfl_xor(s, 4);
      s += __shfl_xor(s, 8);
      if (l15 == 0) red[wid][mt * 16 + quad * 4 + r] = s;
    }
  }
  __syncthreads();
  if (tid < 64) {
    float s = red[0][tid];
#pragma unroll
    for (int w = 1; w < 8; w++) s += red[w][tid];
    rowv[tid] = 1.0f / s;
  }
  __syncthreads();

#pragma unroll
  for (int mt = 0; mt < 4; mt++) {
#pragma unroll
    for (int r = 0; r < 4; r++) {
      int row = mt * 16 + quad * 4 + r;
      float inv = rowv[row];
#pragma unroll
      for (int nt = 0; nt < 4; nt++) {
        int col = wid * 64 + nt * 16 + l15;
        Ob[(size_t)row * 512 + col] = acc[mt][nt][r] * inv;
      }
    }
  }
}

// ---------------------------------------------------------------------------
extern "C" void kernel_launch(void* const* d_in, const int* in_sizes, int n_in,
                              void* d_out, int out_size, void* d_ws, size_t ws_size,
                              hipStream_t stream) {
  const float* lstm_lt = (const float*)d_in[0];   // (64,512,512)
  const float* lstm_rt = (const float*)d_in[1];   // (64,512,512)
  const float* W       = (const float*)d_in[2];   // (512,256)
  const float* diag    = (const float*)d_in[3];   // (256)
  float* out = (float*)d_out;                     // (64,512,512)

  // Workspace: Wt bf16 [256,512] | lt bf16 [32768,256] | rt bf16 [32768,256]
  unsigned short* Wt  = (unsigned short*)d_ws;
  unsigned short* Olt = (unsigned short*)((char*)d_ws + (size_t)256 * 512 * 2);
  unsigned short* Ort = Olt + (size_t)32768 * 256;

  k_wt<<<dim3(256), dim3(128), 0, stream>>>(W, Wt);
  k_proj<<<dim3(256), dim3(512), 0, stream>>>(lstm_lt, lstm_rt, Wt, diag, Olt, Ort);
  k_attn<<<dim3(512), dim3(512), 0, stream>>>(Olt, Ort, out);
}

// Round 4
// 217.132 us; speedup vs baseline: 1.1643x; 1.1643x over previous
//
#include <hip/hip_runtime.h>

typedef __attribute__((ext_vector_type(8))) __bf16 bf16x8;
typedef __attribute__((ext_vector_type(4))) float f32x4;

#define DI __device__ __forceinline__

// float -> bf16 bits, RNE
DI unsigned short f2bf(float x) {
  unsigned u = __float_as_uint(x);
  u += 0x7fffu + ((u >> 16) & 1u);
  return (unsigned short)(u >> 16);
}

DI bf16x8 cvt8(f32x4 lo, f32x4 hi) {
  bf16x8 r;
  r[0] = (__bf16)lo.x; r[1] = (__bf16)lo.y; r[2] = (__bf16)lo.z; r[3] = (__bf16)lo.w;
  r[4] = (__bf16)hi.x; r[5] = (__bf16)hi.y; r[6] = (__bf16)hi.z; r[7] = (__bf16)hi.w;
  return r;
}

DI float tanh_fast(float x) {
  float ax = fabsf(x);
  float e = __expf(-2.0f * ax);
  float t = (1.0f - e) / (1.0f + e);
  return x < 0.0f ? -t : t;
}

// async global->LDS, 16 B per lane. LDS dst = wave-uniform base + lane*16.
DI void glds16(const void* gptr, void* lptr) {
  __builtin_amdgcn_global_load_lds(
      (const __attribute__((address_space(1))) unsigned int*)gptr,
      (__attribute__((address_space(3))) unsigned int*)lptr, 16, 0, 0);
}

// ---------------------------------------------------------------------------
// Fragment-tiled layout for the stationary (B-side) operands:
//   element (n, k) lives at  [(n>>4)*KW + (k>>5)] * 512 u16
//                            + ((k>>3)&3)*128 + (n&15)*8 + (k&7)
// (KW = K/32 windows). One (16n x 32k) sub-tile = 1 KB in EXACT mfma b-frag
// lane order: lane = ((k&31)>>3)*16 + (n&15), 16 B per lane. A wave loads a
// whole fragment with ONE fully-coalesced 16-B/lane global read -> no LDS.
// ---------------------------------------------------------------------------

// Kernel 0: W [512(k),256(n)] fp32 -> Wt fragment-tiled bf16 (KW=16).
__global__ void k_wt(const float* __restrict__ W, unsigned short* __restrict__ Wt) {
  int n  = blockIdx.x;      // 0..255
  int k8 = threadIdx.x;     // 0..63 (8 k per thread)
  unsigned v[8];
#pragma unroll
  for (int j = 0; j < 8; j++) v[j] = f2bf(W[(k8 * 8 + j) * 256 + n]);
  uint4 p;
  p.x = v[0] | (v[1] << 16);
  p.y = v[2] | (v[3] << 16);
  p.z = v[4] | (v[5] << 16);
  p.w = v[6] | (v[7] << 16);
  size_t idx = ((size_t)(n >> 4) * 16 + (k8 >> 2)) * 512 + (k8 & 3) * 128 + (n & 15) * 8;
  *(uint4*)&Wt[idx] = p;
}

// ---------------------------------------------------------------------------
// Kernel 1: projection GEMM. M=65536, K=512, N=256. Tile 128x256, 8 waves
// (2x4 of 64x64), BK=64, 8 K-steps.
// A: glds16-staged fp32 into a single 32 KB LDS buffer (R0-proven swizzle).
// B: NO LDS -- direct global->VGPR fragment loads from fragment-tiled Wt
//    (issued before the stage barrier so they complete with it).
// Staged-through-LDS bytes per iteration halve: 268 MB -> 134 MB.
// Olt written row-major (k_attn A-side); Ort written FRAGMENT-TILED
// (k_attn B-side reads it direct-to-reg).
// ---------------------------------------------------------------------------
__global__ __launch_bounds__(512, 4) void k_proj(
    const float* __restrict__ Alt, const float* __restrict__ Art,
    const unsigned short* __restrict__ Wt, const float* __restrict__ diag,
    unsigned short* __restrict__ Olt, unsigned short* __restrict__ Ort) {
  __shared__ __align__(16) float As[128 * 64];   // 32 KB

  int bx = blockIdx.x;              // 0..511
  bool is_lt = bx < 256;
  int m0 = (is_lt ? bx : bx - 256) * 128;
  const char* Abase = (const char*)((is_lt ? Alt : Art) + (size_t)m0 * 512);
  const char* Bt = (const char*)Wt;

  int tid  = threadIdx.x;
  int lane = tid & 63;
  int wid  = tid >> 6;              // 0..7
  int wm   = wid >> 2;              // 0..1
  int wn   = wid & 3;               // 0..3
  int l15  = lane & 15;
  int quad = lane >> 4;
  int r7   = l15 & 7;

  // A glds source swizzle (R0-proven): 4 rows/glds, 16 chunks of 16 B per row.
  int lr4 = lane >> 4, c16 = lane & 15;
  int aoff = lr4 * 2048 + ((c16 ^ lr4) << 4);          // A row stride 2048 B

  char* AsB = (char*)As;

  f32x4 zero = {0.0f, 0.0f, 0.0f, 0.0f};
  f32x4 acc[4][4];
#pragma unroll
  for (int i = 0; i < 4; i++)
#pragma unroll
    for (int j = 0; j < 4; j++) acc[i][j] = zero;

  for (int k0 = 0; k0 < 512; k0 += 64) {
    // --- B fragments for this K-step: 8 direct coalesced loads (regs) ---
    uint4 bv[2][4];
#pragma unroll
    for (int ks = 0; ks < 2; ks++)
#pragma unroll
      for (int nt = 0; nt < 4; nt++)
        bv[ks][nt] = *(const uint4*)(
            Bt + (((size_t)(wn * 4 + nt) * 16 + (k0 >> 5) + ks) << 10) + lane * 16);

    // --- stage A (fp32): 32 glds, 4 per wave; inst j covers rows 4j..4j+3 ---
#pragma unroll
    for (int i = 0; i < 4; i++) {
      int j = wid * 4 + i;
      glds16(Abase + (size_t)j * 8192 + (size_t)k0 * 4 + (aoff ^ ((j & 1) << 6)),
             AsB + j * 1024);
    }
    __syncthreads();   // drains glds + bv loads

#pragma unroll
    for (int ks = 0; ks < 2; ks++) {
      bf16x8 a[4];
#pragma unroll
      for (int mt = 0; mt < 4; mt++) {
        int row = wm * 64 + mt * 16 + l15;
        int c0 = ks * 8 + quad * 2;
        f32x4 lo = *(const f32x4*)(AsB + row * 256 + (((c0    ) ^ r7) << 4));
        f32x4 hi = *(const f32x4*)(AsB + row * 256 + (((c0 + 1) ^ r7) << 4));
        a[mt] = cvt8(lo, hi);
      }
      __builtin_amdgcn_s_setprio(1);
#pragma unroll
      for (int mt = 0; mt < 4; mt++)
#pragma unroll
        for (int nt = 0; nt < 4; nt++)
          acc[mt][nt] = __builtin_amdgcn_mfma_f32_16x16x32_bf16(
              a[mt], __builtin_bit_cast(bf16x8, bv[ks][nt]), acc[mt][nt], 0, 0, 0);
      __builtin_amdgcn_s_setprio(0);
    }
    __syncthreads();   // protect As before next step's staging
  }

  // Epilogue: tanh, diag scale (lt only), bf16 store.
  float dscale[4];
#pragma unroll
  for (int nt = 0; nt < 4; nt++)
    dscale[nt] = is_lt ? diag[wn * 64 + nt * 16 + l15] : 1.0f;

  if (is_lt) {
    unsigned short* O = Olt + (size_t)m0 * 256;
#pragma unroll
    for (int mt = 0; mt < 4; mt++)
#pragma unroll
      for (int r = 0; r < 4; r++) {
        int row = wm * 64 + mt * 16 + quad * 4 + r;
#pragma unroll
        for (int nt = 0; nt < 4; nt++) {
          int col = wn * 64 + nt * 16 + l15;
          O[(size_t)row * 256 + col] = f2bf(tanh_fast(acc[mt][nt][r]) * dscale[nt]);
        }
      }
  } else {
    // Fragment-tiled store (KW = 256/32 = 8 per batch of 512 rows).
#pragma unroll
    for (int mt = 0; mt < 4; mt++)
#pragma unroll
      for (int r = 0; r < 4; r++) {
        int row = wm * 64 + mt * 16 + quad * 4 + r;
        int m = m0 + row;
        int bb = m >> 9, rr = m & 511;
#pragma unroll
        for (int nt = 0; nt < 4; nt++) {
          int d = wn * 64 + nt * 16 + l15;
          size_t idx = (size_t)bb * 131072 +
                       ((size_t)(rr >> 4) * 8 + (d >> 5)) * 512 +
                       ((d >> 3) & 3) * 128 + (rr & 15) * 8 + (d & 7);
          Ort[idx] = f2bf(tanh_fast(acc[mt][nt][r]));
        }
      }
  }
}

// ---------------------------------------------------------------------------
// Kernel 2: per-batch logits (lt_b @ rt_b^T, K=256) + fused exact softmax.
// Block 64(L) x 512(R), 8 waves (64x64 tiles, wid = col-group).
// L tile (64x256 bf16, 32 KB) glds-staged ONCE in the prologue (swizzled).
// R fragments read DIRECT global->VGPR from fragment-tiled Ort: the K-loop
// has NO barriers at all -- 8 iterations of {4 coalesced loads + 4 ds_reads
// + 16 MFMA}, freely pipelined by the compiler. XCD batch swizzle retained.
// ---------------------------------------------------------------------------
__global__ __launch_bounds__(512, 4) void k_attn(
    const unsigned short* __restrict__ Lt, const unsigned short* __restrict__ Rt,
    float* __restrict__ Out) {
  __shared__ __align__(16) unsigned short Ls[64 * 256];   // 32 KB
  __shared__ float red[8][64];
  __shared__ float rowv[64];

  int bx = blockIdx.x;                       // 0..511
  int b  = (bx & 7) * 8 + ((bx >> 3) & 7);   // batch, XCD-co-located
  int l0 = (bx >> 6) * 64;
  const char* Lb = (const char*)(Lt + ((size_t)b * 512 + l0) * 256);
  const char* Rb = (const char*)Rt + (size_t)b * 262144;   // tiled, 256 KB/batch
  float* Ob = Out + ((size_t)b * 512 + l0) * 512;

  int tid  = threadIdx.x;
  int lane = tid & 63;
  int wid  = tid >> 6;              // 0..7 -> 64-col group
  int l15  = lane & 15;
  int quad = lane >> 4;
  int r7   = l15 & 7;

  char* LsB = (char*)Ls;

  f32x4 zero = {0.0f, 0.0f, 0.0f, 0.0f};
  f32x4 acc[4][4];
#pragma unroll
  for (int i = 0; i < 4; i++)
#pragma unroll
    for (int j = 0; j < 4; j++) acc[i][j] = zero;

  // ---- prologue: stage whole-K L tile (32 glds, 4/wave, 2 rows each) ----
  // Row = 512 B = 32 chunks; chunk c stored at slot c^(row&7) (pre-swizzled
  // per-lane global source, flat LDS dest).
#pragma unroll
  for (int i = 0; i < 4; i++) {
    int grow = wid * 8 + i * 2 + (lane >> 5);          // this lane's source row
    glds16(Lb + (size_t)grow * 512 + (((lane & 31) ^ (grow & 7)) << 4),
           LsB + (wid * 8 + i * 2) * 512 + (lane & 31) * 16 + (lane >> 5) * 512);
  }
  __syncthreads();

  // ---- barrier-free K-loop: 8 windows of 32 k ----
  for (int t = 0; t < 8; t++) {
    uint4 rv[4];
#pragma unroll
    for (int nt = 0; nt < 4; nt++)
      rv[nt] = *(const uint4*)(
          Rb + (((size_t)(wid * 4 + nt) * 8 + t) << 10) + lane * 16);
    bf16x8 a[4];
#pragma unroll
    for (int mt = 0; mt < 4; mt++) {
      int row = mt * 16 + l15;
      a[mt] = *(const bf16x8*)(LsB + row * 512 + (((t * 4 + quad) ^ r7) << 4));
    }
    __builtin_amdgcn_s_setprio(1);
#pragma unroll
    for (int mt = 0; mt < 4; mt++)
#pragma unroll
      for (int nt = 0; nt < 4; nt++)
        acc[mt][nt] = __builtin_amdgcn_mfma_f32_16x16x32_bf16(
            a[mt], __builtin_bit_cast(bf16x8, rv[nt]), acc[mt][nt], 0, 0, 0);
    __builtin_amdgcn_s_setprio(0);
  }

  // -------- softmax over the 512-wide row (8 col-groups) --------
#pragma unroll
  for (int mt = 0; mt < 4; mt++) {
#pragma unroll
    for (int r = 0; r < 4; r++) {
      float m = fmaxf(fmaxf(acc[mt][0][r], acc[mt][1][r]),
                      fmaxf(acc[mt][2][r], acc[mt][3][r]));
      m = fmaxf(m, __shfl_xor(m, 1));
      m = fmaxf(m, __shfl_xor(m, 2));
      m = fmaxf(m, __shfl_xor(m, 4));
      m = fmaxf(m, __shfl_xor(m, 8));
      if (l15 == 0) red[wid][mt * 16 + quad * 4 + r] = m;
    }
  }
  __syncthreads();
  if (tid < 64) {
    float m = red[0][tid];
#pragma unroll
    for (int w = 1; w < 8; w++) m = fmaxf(m, red[w][tid]);
    rowv[tid] = m;
  }
  __syncthreads();

#pragma unroll
  for (int mt = 0; mt < 4; mt++) {
#pragma unroll
    for (int r = 0; r < 4; r++) {
      float base = rowv[mt * 16 + quad * 4 + r];
      float s = 0.0f;
#pragma unroll
      for (int nt = 0; nt < 4; nt++) {
        float e = __expf(acc[mt][nt][r] - base);
        acc[mt][nt][r] = e;
        s += e;
      }
      s += __shfl_xor(s, 1);
      s += __shfl_xor(s, 2);
      s += __shfl_xor(s, 4);
      s += __shfl_xor(s, 8);
      if (l15 == 0) red[wid][mt * 16 + quad * 4 + r] = s;
    }
  }
  __syncthreads();
  if (tid < 64) {
    float s = red[0][tid];
#pragma unroll
    for (int w = 1; w < 8; w++) s += red[w][tid];
    rowv[tid] = 1.0f / s;
  }
  __syncthreads();

#pragma unroll
  for (int mt = 0; mt < 4; mt++) {
#pragma unroll
    for (int r = 0; r < 4; r++) {
      int row = mt * 16 + quad * 4 + r;
      float inv = rowv[row];
#pragma unroll
      for (int nt = 0; nt < 4; nt++) {
        int col = wid * 64 + nt * 16 + l15;
        Ob[(size_t)row * 512 + col] = acc[mt][nt][r] * inv;
      }
    }
  }
}

// ---------------------------------------------------------------------------
extern "C" void kernel_launch(void* const* d_in, const int* in_sizes, int n_in,
                              void* d_out, int out_size, void* d_ws, size_t ws_size,
                              hipStream_t stream) {
  const float* lstm_lt = (const float*)d_in[0];   // (64,512,512)
  const float* lstm_rt = (const float*)d_in[1];   // (64,512,512)
  const float* W       = (const float*)d_in[2];   // (512,256)
  const float* diag    = (const float*)d_in[3];   // (256)
  float* out = (float*)d_out;                     // (64,512,512)

  // Workspace: Wt tiled bf16 [256*512] | Olt row-major bf16 | Ort tiled bf16
  unsigned short* Wt  = (unsigned short*)d_ws;
  unsigned short* Olt = (unsigned short*)((char*)d_ws + (size_t)256 * 512 * 2);
  unsigned short* Ort = Olt + (size_t)32768 * 256;

  k_wt<<<dim3(256), dim3(64), 0, stream>>>(W, Wt);
  k_proj<<<dim3(512), dim3(512), 0, stream>>>(lstm_lt, lstm_rt, Wt, diag, Olt, Ort);
  k_attn<<<dim3(512), dim3(512), 0, stream>>>(Olt, Ort, out);
}